// Round 2
// baseline (515.691 us; speedup 1.0000x reference)
//
#include <hip/hip_runtime.h>
#include <hip/hip_bf16.h>
#include <cstdint>
#include <cstddef>

#define NE 16
#define NB 32768
#define LATENT 128
#define HID 64
#define CLASSES 10
#define WPE 32          // token-tile blocks per expert (64 tokens/tile)

// ---------------------------------------------------------------------------
// Assign (probe fused): decide mask storage (byte-bool vs 4-byte word), then
// bucket token ids per expert. Byte offsets b=1+4t (t<32) are nonzero for
// byte-bool one-hot columns, but always 0x00 for int32(1)/float32(1.0) words.
// ---------------------------------------------------------------------------
__global__ void assign_kernel(const void* __restrict__ mask,
                              int* __restrict__ counts,
                              unsigned short* __restrict__ lists) {
    __shared__ int sMode;
    const int tid = threadIdx.x;
    if (tid == 0) sMode = 0;
    __syncthreads();
    if (tid < 32) {
        const unsigned char* mb = (const unsigned char*)mask;
        int b = 1 + 4 * tid;
        int nz = 0;
        for (int e = 0; e < NE; ++e) nz |= mb[(size_t)e * NB + b];
        if (nz) atomicOr(&sMode, 1);
    }
    __syncthreads();
    const int mode = sMode;

    int b = blockIdx.x * blockDim.x + tid;
    if (b >= NB) return;
    int myE = 0;
    if (mode) {
        const unsigned char* m = (const unsigned char*)mask;
        for (int e = 0; e < NE; ++e)
            if (m[(size_t)e * NB + b]) { myE = e; break; }
    } else {
        const int* m = (const int*)mask;   // also correct for float32 0.0/1.0
        for (int e = 0; e < NE; ++e)
            if (m[(size_t)e * NB + b] != 0) { myE = e; break; }
    }
    int pos = atomicAdd(&counts[myE], 1);
    lists[myE * NB + pos] = (unsigned short)b;
}

// ---------------------------------------------------------------------------
// Expert MLP, lane = token. Block = 128 threads = 2 waves; each wave computes
// half the hidden channels (j-split), x/h exchanged via LDS transposed
// [channel][token] (conflict-free b32, per-lane distinct data). Weights are
// wave-uniform -> scalar s_load (readfirstlane forces SGPR-ness of wave id).
// Inner loop: 1 ds_read_b32 + 32 independent v_fma -> VALU-bound.
// ---------------------------------------------------------------------------
__global__ __launch_bounds__(128) void expert_kernel(
    const float* __restrict__ latent,
    const float* __restrict__ W1, const float* __restrict__ b1,
    const float* __restrict__ W2, const float* __restrict__ b2,
    const float* __restrict__ W3, const float* __restrict__ b3,
    const int* __restrict__ counts,
    const unsigned short* __restrict__ lists,
    float* __restrict__ out)
{
    __shared__ float sX[LATENT * 64];   // [l][tok] transposed, 32 KB; reused for h1,h2

    const int e   = blockIdx.x / WPE;
    const int blk = blockIdx.x % WPE;
    const int tid = threadIdx.x;
    const int lane = tid & 63;
    const int jh  = __builtin_amdgcn_readfirstlane(tid >> 6);   // wave id: 0/1, SGPR

    const int cnt = counts[e];
    const int ntiles = (cnt + 63) >> 6;
    const unsigned short* mylist = lists + e * NB;

    const float* w1e = W1 + (size_t)e * LATENT * HID + jh * 32;
    const float* w2e = W2 + (size_t)e * HID * HID + jh * 32;
    const float* w3e = W3 + (size_t)e * HID * CLASSES + jh * 5;
    const float* b1e = b1 + e * HID + jh * 32;
    const float* b2e = b2 + e * HID + jh * 32;
    const float* b3e = b3 + e * CLASSES + jh * 5;

    for (int tile = blk; tile < ntiles; tile += WPE) {
        const int base = tile * 64;

        // ---- stage 64 token rows into sX[l][tok] (transposed) ----
        {
            const int s = tid & 63, half = tid >> 6;   // token slot, 64-float half
            int idx = base + s;
            if (idx >= cnt) idx = cnt - 1;
            const int tok = mylist[idx];
            const float4* src = (const float4*)
                (latent + ((size_t)e * NB + tok) * LATENT + half * 64);
            #pragma unroll
            for (int i = 0; i < 16; ++i) {
                float4 v = src[i];
                int l = half * 64 + i * 4;
                sX[(l + 0) * 64 + s] = v.x;
                sX[(l + 1) * 64 + s] = v.y;
                sX[(l + 2) * 64 + s] = v.z;
                sX[(l + 3) * 64 + s] = v.w;
            }
        }
        __syncthreads();

        // ---- layer 1: 128 -> 64 (this wave: 32 channels), relu ----
        float acc[32];
        #pragma unroll
        for (int j = 0; j < 32; ++j) acc[j] = b1e[j];
        for (int l = 0; l < LATENT; ++l) {
            float x = sX[l * 64 + lane];
            const float* wr = w1e + l * HID;
            #pragma unroll
            for (int j = 0; j < 32; ++j) acc[j] = fmaf(x, wr[j], acc[j]);
        }
        __syncthreads();                       // all reads of sX done
        #pragma unroll
        for (int j = 0; j < 32; ++j)
            sX[(jh * 32 + j) * 64 + lane] = fmaxf(acc[j], 0.f);
        __syncthreads();

        // ---- layer 2: 64 -> 64 (this wave: 32 channels), relu ----
        float acc2[32];
        #pragma unroll
        for (int j = 0; j < 32; ++j) acc2[j] = b2e[j];
        for (int l = 0; l < HID; ++l) {
            float x = sX[l * 64 + lane];
            const float* wr = w2e + l * HID;
            #pragma unroll
            for (int j = 0; j < 32; ++j) acc2[j] = fmaf(x, wr[j], acc2[j]);
        }
        __syncthreads();                       // all reads of h1 done
        #pragma unroll
        for (int j = 0; j < 32; ++j)
            sX[(jh * 32 + j) * 64 + lane] = fmaxf(acc2[j], 0.f);
        __syncthreads();

        // ---- layer 3: 64 -> 10 (this wave: 5 classes), no relu ----
        float a3[5];
        #pragma unroll
        for (int c = 0; c < 5; ++c) a3[c] = b3e[c];
        for (int l = 0; l < HID; ++l) {
            float x = sX[l * 64 + lane];
            const float* wr = w3e + l * CLASSES;
            #pragma unroll
            for (int c = 0; c < 5; ++c) a3[c] = fmaf(x, wr[c], a3[c]);
        }
        {
            int slot = base + lane;
            if (slot < cnt) {
                int tok = mylist[slot];
                float* o = out + (size_t)tok * CLASSES + jh * 5;
                #pragma unroll
                for (int c = 0; c < 5; ++c) o[c] = a3[c];
            }
        }
        __syncthreads();                       // protect sX before next staging
    }
}

extern "C" void kernel_launch(void* const* d_in, const int* in_sizes, int n_in,
                              void* d_out, int out_size, void* d_ws, size_t ws_size,
                              hipStream_t stream) {
    // inputs: 0=x(unused), 1=mask, 2=latent, 3=W1, 4=b1, 5=W2, 6=b2, 7=W3, 8=b3
    const void*  mask   = d_in[1];
    const float* latent = (const float*)d_in[2];
    const float* W1 = (const float*)d_in[3];
    const float* b1 = (const float*)d_in[4];
    const float* W2 = (const float*)d_in[5];
    const float* b2 = (const float*)d_in[6];
    const float* W3 = (const float*)d_in[7];
    const float* b3 = (const float*)d_in[8];
    float* out = (float*)d_out;

    int* counts = (int*)d_ws;                                     // 64 B
    unsigned short* lists = (unsigned short*)((char*)d_ws + 128); // 1 MB

    hipMemsetAsync(d_ws, 0, 128, stream);
    assign_kernel<<<NB / 256, 256, 0, stream>>>(mask, counts, lists);
    expert_kernel<<<NE * WPE, 128, 0, stream>>>(latent, W1, b1, W2, b2, W3, b3,
                                                counts, lists, out);
}

// Round 3
// 404.840 us; speedup vs baseline: 1.2738x; 1.2738x over previous
//
#include <hip/hip_runtime.h>
#include <hip/hip_bf16.h>
#include <cstdint>
#include <cstddef>

#define NE 16
#define NB 32768
#define LATENT 128
#define HID 64
#define CLASSES 10
#define WPE 32          // token-tile blocks per expert (64 tokens/tile)

// ---------------------------------------------------------------------------
// Assign (probe fused): decide mask storage (byte-bool vs 4-byte word), then
// bucket token ids per expert. LDS per-block histogram -> 16 global atomics
// per block (was 256) to avoid same-address atomic serialization.
// Byte offsets b=1+4t (t<32) are nonzero for byte-bool one-hot columns, but
// always 0x00 for int32(1)/float32(1.0) words.
// ---------------------------------------------------------------------------
__global__ __launch_bounds__(256) void assign_kernel(
    const void* __restrict__ mask,
    int* __restrict__ counts,
    unsigned short* __restrict__ lists) {
    __shared__ int sMode;
    __shared__ int lCount[NE];
    __shared__ int gBase[NE];
    __shared__ unsigned short lList[NE][256];

    const int tid = threadIdx.x;
    if (tid == 0) sMode = 0;
    if (tid < NE) lCount[tid] = 0;
    __syncthreads();
    if (tid < 32) {
        const unsigned char* mb = (const unsigned char*)mask;
        int b = 1 + 4 * tid;
        int nz = 0;
        for (int e = 0; e < NE; ++e) nz |= mb[(size_t)e * NB + b];
        if (nz) atomicOr(&sMode, 1);
    }
    __syncthreads();
    const int mode = sMode;

    const int b = blockIdx.x * 256 + tid;
    int myE = 0;
    if (mode) {
        const unsigned char* m = (const unsigned char*)mask;
        for (int e = 0; e < NE; ++e)
            if (m[(size_t)e * NB + b]) { myE = e; break; }
    } else {
        const int* m = (const int*)mask;   // also correct for float32 0.0/1.0
        for (int e = 0; e < NE; ++e)
            if (m[(size_t)e * NB + b] != 0) { myE = e; break; }
    }
    int pos = atomicAdd(&lCount[myE], 1);
    lList[myE][pos] = (unsigned short)b;
    __syncthreads();

    if (tid < NE) gBase[tid] = atomicAdd(&counts[tid], lCount[tid]);
    __syncthreads();

    for (int e = 0; e < NE; ++e) {
        const int n = lCount[e], g0 = gBase[e];
        for (int i = tid; i < n; i += 256)
            lists[e * NB + g0 + i] = lList[e][i];
    }
}

// ---------------------------------------------------------------------------
// Expert MLP, lane = token, 64-token tiles, 4 waves/block with 4-way channel
// split (16 ch/wave). x/h live in LDS transposed [channel][token]
// (conflict-free b32, 2-way aliasing = free). Weights are wave-uniform ->
// scalar s_loads; inner loop = 1 ds_read_b32 + 16 SGPR-operand v_fma.
// Grid 512 blocks x 4 waves = 2048 waves = 2 waves/SIMD for latency hiding.
// ---------------------------------------------------------------------------
__global__ __launch_bounds__(256) void expert_kernel(
    const float* __restrict__ latent,
    const float* __restrict__ W1, const float* __restrict__ b1,
    const float* __restrict__ W2, const float* __restrict__ b2,
    const float* __restrict__ W3, const float* __restrict__ b3,
    const int* __restrict__ counts,
    const unsigned short* __restrict__ lists,
    float* __restrict__ out)
{
    __shared__ float sX[LATENT * 64];   // [l][tok] transposed, 32 KB; reused for h1,h2

    const int e    = blockIdx.x / WPE;
    const int blk  = blockIdx.x % WPE;
    const int tid  = threadIdx.x;
    const int lane = tid & 63;
    const int jh   = __builtin_amdgcn_readfirstlane(tid >> 6);  // wave id 0..3, SGPR

    const int cnt = counts[e];
    const int ntiles = (cnt + 63) >> 6;
    const unsigned short* mylist = lists + e * NB;

    const float* w1e = W1 + (size_t)e * LATENT * HID + jh * 16;
    const float* w2e = W2 + (size_t)e * HID * HID + jh * 16;
    const float* b1e = b1 + e * HID + jh * 16;
    const float* b2e = b2 + e * HID + jh * 16;
    const float* w3e = W3 + (size_t)e * HID * CLASSES + jh * 5;   // waves 0,1 only
    const float* b3e = b3 + e * CLASSES + jh * 5;

    for (int tile = blk; tile < ntiles; tile += WPE) {
        const int base = tile * 64;

        // ---- stage 64 token rows into sX[l][tok] (transposed) ----
        {
            const int s = lane, q = jh;            // token slot, quarter-row index
            int idx = base + s;
            if (idx >= cnt) idx = cnt - 1;
            const int tok = mylist[idx];
            const float4* src = (const float4*)
                (latent + ((size_t)e * NB + tok) * LATENT + q * 32);
            #pragma unroll
            for (int i = 0; i < 8; ++i) {
                float4 v = src[i];
                int l = q * 32 + i * 4;
                sX[(l + 0) * 64 + s] = v.x;
                sX[(l + 1) * 64 + s] = v.y;
                sX[(l + 2) * 64 + s] = v.z;
                sX[(l + 3) * 64 + s] = v.w;
            }
        }
        __syncthreads();

        // ---- layer 1: 128 -> 64 (this wave: 16 channels), relu ----
        float acc[16];
        #pragma unroll
        for (int j = 0; j < 16; ++j) acc[j] = b1e[j];
        #pragma unroll 4
        for (int l = 0; l < LATENT; ++l) {
            float x = sX[l * 64 + lane];
            const float* wr = w1e + l * HID;
            #pragma unroll
            for (int j = 0; j < 16; ++j) acc[j] = fmaf(x, wr[j], acc[j]);
        }
        __syncthreads();                       // all reads of sX done
        #pragma unroll
        for (int j = 0; j < 16; ++j)
            sX[(jh * 16 + j) * 64 + lane] = fmaxf(acc[j], 0.f);
        __syncthreads();

        // ---- layer 2: 64 -> 64 (this wave: 16 channels), relu ----
        float acc2[16];
        #pragma unroll
        for (int j = 0; j < 16; ++j) acc2[j] = b2e[j];
        #pragma unroll 4
        for (int l = 0; l < HID; ++l) {
            float x = sX[l * 64 + lane];
            const float* wr = w2e + l * HID;
            #pragma unroll
            for (int j = 0; j < 16; ++j) acc2[j] = fmaf(x, wr[j], acc2[j]);
        }
        __syncthreads();                       // all reads of h1 done
        #pragma unroll
        for (int j = 0; j < 16; ++j)
            sX[(jh * 16 + j) * 64 + lane] = fmaxf(acc2[j], 0.f);
        __syncthreads();

        // ---- layer 3: 64 -> 10; waves 0,1 take 5 classes each ----
        if (jh < 2) {
            float a3[5];
            #pragma unroll
            for (int c = 0; c < 5; ++c) a3[c] = b3e[c];
            #pragma unroll 4
            for (int l = 0; l < HID; ++l) {
                float x = sX[l * 64 + lane];
                const float* wr = w3e + l * CLASSES;
                #pragma unroll
                for (int c = 0; c < 5; ++c) a3[c] = fmaf(x, wr[c], a3[c]);
            }
            int slot = base + lane;
            if (slot < cnt) {
                int tok = mylist[slot];
                float* o = out + (size_t)tok * CLASSES + jh * 5;
                #pragma unroll
                for (int c = 0; c < 5; ++c) o[c] = a3[c];
            }
        }
        __syncthreads();                       // protect sX before next staging
    }
}

extern "C" void kernel_launch(void* const* d_in, const int* in_sizes, int n_in,
                              void* d_out, int out_size, void* d_ws, size_t ws_size,
                              hipStream_t stream) {
    // inputs: 0=x(unused), 1=mask, 2=latent, 3=W1, 4=b1, 5=W2, 6=b2, 7=W3, 8=b3
    const void*  mask   = d_in[1];
    const float* latent = (const float*)d_in[2];
    const float* W1 = (const float*)d_in[3];
    const float* b1 = (const float*)d_in[4];
    const float* W2 = (const float*)d_in[5];
    const float* b2 = (const float*)d_in[6];
    const float* W3 = (const float*)d_in[7];
    const float* b3 = (const float*)d_in[8];
    float* out = (float*)d_out;

    int* counts = (int*)d_ws;                                     // 64 B
    unsigned short* lists = (unsigned short*)((char*)d_ws + 128); // 1 MB

    hipMemsetAsync(d_ws, 0, 64, stream);
    assign_kernel<<<NB / 256, 256, 0, stream>>>(mask, counts, lists);
    expert_kernel<<<NE * WPE, 256, 0, stream>>>(latent, W1, b1, W2, b2, W3, b3,
                                                counts, lists, out);
}